// Round 7
// baseline (563.914 us; speedup 1.0000x reference)
//
#include <hip/hip_runtime.h>
#include <hip/hip_bf16.h>
#include <cstdint>
#include <type_traits>

typedef __attribute__((ext_vector_type(8))) __bf16 bf16x8;
typedef __attribute__((ext_vector_type(8))) short short8;
typedef __attribute__((ext_vector_type(4))) float f32x4;
using u16 = unsigned short;

// ---- MFMA fragment-type autodetect ----
template <typename T, typename = void> struct mfma_ok : std::false_type {};
template <typename T>
struct mfma_ok<T, std::void_t<decltype(__builtin_amdgcn_mfma_f32_16x16x32_bf16(
    std::declval<T>(), std::declval<T>(), std::declval<f32x4>(), 0, 0, 0))>>
    : std::true_type {};
using frag_t = std::conditional_t<mfma_ok<bf16x8>::value, bf16x8, short8>;
static_assert(sizeof(frag_t) == 16, "frag must be 4 VGPRs");

template <typename T>
__device__ __forceinline__ f32x4 MFMA(T a, T b, f32x4 c) {
  return __builtin_amdgcn_mfma_f32_16x16x32_bf16(a, b, c, 0, 0, 0);
}

__device__ __forceinline__ void gl_lds16(const u16* g, u16* l) {
  __builtin_amdgcn_global_load_lds(
      (const __attribute__((address_space(1))) unsigned int*)g,
      (__attribute__((address_space(3))) unsigned int*)l, 16, 0, 0);
}

__device__ __forceinline__ u16 f2bf(float v) {
  __hip_bfloat16 h = __float2bfloat16(v);
  return __builtin_bit_cast(u16, h);
}

// bijective XCD swizzle (nwg % 8 == 0 for all our grids)
__device__ __forceinline__ int xcd_swz(int wid, int nwg) {
  return (wid & 7) * (nwg >> 3) + (wid >> 3);
}

// ---------------------------------------------------------------------------
// GEMM core v7 — m97-faithful. 128x128 tile, 256 threads / 4 waves (2Mx2N),
// per-wave 64x64 -> acc[4][4] (64 VGPR). BK=32, SINGLE 16KB LDS buffer,
// plain __syncthreads() x2 per K-step, no asm, no setprio. Overlap comes
// from 3-4 independent blocks/CU (m114 mechanism), not intra-block
// pipelining. [128][32] layout: gl_lds dests and all frag ds_read_b128s
// are contiguous 1KB wave-sweeps -> zero bank conflicts, zero swizzle.
// A[row][k] row-major (lda); B[vcol][k] row-major (ldb). K % 32 == 0.
// ---------------------------------------------------------------------------
__device__ __forceinline__ void gemm128(
    const u16* __restrict__ A, int lda,
    const u16* __restrict__ B, int ldb, int K,
    u16* lds, f32x4 (&acc)[4][4])
{
  const int t = threadIdx.x;          // 0..255
  const int l = t & 63;
  const int w = t >> 6;               // 0..3
  const int wm = w >> 1, wc = w & 1;  // 2x2 wave grid

  const u16* gA = A + (t >> 2) * lda + (t & 3) * 8;
  const u16* gB = B + (t >> 2) * ldb + (t & 3) * 8;

  const int lr = l & 15, lk = l >> 4;
  const int ab = (wm * 64 + lr) * 32 + lk * 8;
  const int bb = 4096 + (wc * 64 + lr) * 32 + lk * 8;

  const int nt = K >> 5;
  for (int kt = 0; kt < nt; ++kt) {
    const u16* a_ = gA + kt * 32;
    const u16* b_ = gB + kt * 32;
    gl_lds16(a_,            lds + w * 512);
    gl_lds16(a_ + 64 * lda, lds + 2048 + w * 512);
    gl_lds16(b_,            lds + 4096 + w * 512);
    gl_lds16(b_ + 64 * ldb, lds + 6144 + w * 512);
    __syncthreads();   // compiler drains vmcnt(0) before s_barrier

    frag_t a[4], b[4];
#pragma unroll
    for (int fm = 0; fm < 4; ++fm)
      a[fm] = *(const frag_t*)(lds + ab + fm * 512);
#pragma unroll
    for (int fn = 0; fn < 4; ++fn)
      b[fn] = *(const frag_t*)(lds + bb + fn * 512);
#pragma unroll
    for (int fn = 0; fn < 4; ++fn)
#pragma unroll
      for (int fm = 0; fm < 4; ++fm)
        acc[fm][fn] = MFMA(a[fm], b[fn], acc[fm][fn]);
    __syncthreads();   // reads done before next stage overwrites
  }
}

// ---------------------------------------------------------------------------
// Kernel 1: weight repack f32 -> bf16, layouts for 128-col virtual tiles.
// Wint[32 nt][128 vcols][1024] : vcol = wc*64 + gate*16 + c16,
//                                actual col = nt*32 + wc*16 + c16
// Rint[32 nt][128 vcols][128]  : head = nt>>2,
//                                colInHead = (nt&3)*32 + wc*16 + c16
// upint[22 vt][128 vcols][1024]: vcol = wc*64 + fn*16 + c16, half = fn>>1,
//                                actual a = vt*64 + wc*32 + (fn&1)*16 + c16
// dnp[1024][1408] k-padded zeros
// ---------------------------------------------------------------------------
__global__ __launch_bounds__(256) void prep_kernel(
    const float* __restrict__ Wi, const float* __restrict__ Wf,
    const float* __restrict__ Wz, const float* __restrict__ Wo,
    const float* __restrict__ Ri, const float* __restrict__ Rf,
    const float* __restrict__ Rz, const float* __restrict__ Ro,
    const float* __restrict__ upw, const float* __restrict__ dnw,
    u16* __restrict__ Wint, u16* __restrict__ Rint,
    u16* __restrict__ upint, u16* __restrict__ dnp)
{
  const int stride = gridDim.x * 256;
  for (int i = blockIdx.x * 256 + threadIdx.x; i < 9043968; i += stride) {
    if (i < 4194304) {
      const int nt = i >> 17, vcol = (i >> 10) & 127, k = i & 1023;
      const int wc = vcol >> 6, g = (vcol >> 4) & 3, c16 = vcol & 15;
      const int col = nt * 32 + wc * 16 + c16;
      const float* W = (g == 0) ? Wi : (g == 1) ? Wf : (g == 2) ? Wz : Wo;
      Wint[i] = f2bf(W[col * 1024 + k]);
    } else if (i < 4718592) {
      const int j = i - 4194304;
      const int nt = j >> 14, vcol = (j >> 7) & 127, k = j & 127;
      const int wc = vcol >> 6, g = (vcol >> 4) & 3, c16 = vcol & 15;
      const int head = nt >> 2;
      const int colInHead = (nt & 3) * 32 + wc * 16 + c16;
      const float* R = (g == 0) ? Ri : (g == 1) ? Rf : (g == 2) ? Rz : Ro;
      Rint[j] = f2bf(R[head * 16384 + colInHead * 128 + k]);
    } else if (i < 7602176) {
      const int j = i - 4718592;
      const int vt = j >> 17, vcol = (j >> 10) & 127, k = j & 1023;
      const int wc = vcol >> 6, fn = (vcol >> 4) & 3, c16 = vcol & 15;
      const int half = fn >> 1;
      const int a = vt * 64 + wc * 32 + (fn & 1) * 16 + c16;
      upint[j] = (a < 1365) ? f2bf(upw[(half * 1365 + a) * 1024 + k]) : (u16)0;
    } else {
      const int j = i - 7602176;
      const int row = j / 1408, k = j - row * 1408;
      dnp[j] = (k < 1365) ? f2bf(dnw[row * 1365 + k]) : (u16)0;
    }
  }
}

// ---------------------------------------------------------------------------
// Kernel 2: LayerNorm(seq) -> x bf16 ; h0 -> bf16. One row per block.
// ---------------------------------------------------------------------------
__global__ __launch_bounds__(256) void ln_kernel(
    const float* __restrict__ seq, const float* __restrict__ h0,
    const float* __restrict__ lnw, const float* __restrict__ lnb,
    u16* __restrict__ xb, u16* __restrict__ h0b)
{
  const int row = blockIdx.x;
  const int t = threadIdx.x;
  const float4 v = ((const float4*)(seq + (size_t)row * 1024))[t];
  float s = v.x + v.y + v.z + v.w;
  float q = v.x * v.x + v.y * v.y + v.z * v.z + v.w * v.w;
#pragma unroll
  for (int o = 32; o >= 1; o >>= 1) { s += __shfl_xor(s, o); q += __shfl_xor(q, o); }
  __shared__ float sm[8];
  const int l = t & 63, w = t >> 6;
  if (l == 0) { sm[w] = s; sm[4 + w] = q; }
  __syncthreads();
  s = sm[0] + sm[1] + sm[2] + sm[3];
  q = sm[4] + sm[5] + sm[6] + sm[7];
  const float mu = s * (1.f / 1024.f);
  const float var = q * (1.f / 1024.f) - mu * mu;
  const float rstd = rsqrtf(var + 1e-5f);
  const float4 wv = ((const float4*)lnw)[t];
  const float4 bv = ((const float4*)lnb)[t];
  ushort4 o4;
  o4.x = f2bf((v.x - mu) * rstd * wv.x + bv.x);
  o4.y = f2bf((v.y - mu) * rstd * wv.y + bv.y);
  o4.z = f2bf((v.z - mu) * rstd * wv.z + bv.z);
  o4.w = f2bf((v.w - mu) * rstd * wv.w + bv.w);
  ((ushort4*)(xb + (size_t)row * 1024))[t] = o4;
  const float4 h = ((const float4*)(h0 + (size_t)row * 1024))[t];
  ushort4 h4;
  h4.x = f2bf(h.x); h4.y = f2bf(h.y); h4.z = f2bf(h.z); h4.w = f2bf(h.w);
  ((ushort4*)(h0b + (size_t)row * 1024))[t] = h4;
}

// ---------------------------------------------------------------------------
// Kernel 3: fused 4-gate GEMM (+recurrent block-diag) + sLSTM pointwise.
// Block: 128 rows x 32 actual cols x 4 gates (128 vcols). Wave: 64 rows x
// 16 actual cols x 4 gates (fn = gate) -> pointwise fully in-register.
// ---------------------------------------------------------------------------
__global__ __launch_bounds__(256, 3) void gate_kernel(
    const u16* __restrict__ xb, const u16* __restrict__ h0b,
    const u16* __restrict__ Wint, const u16* __restrict__ Rint,
    const float* __restrict__ bi, const float* __restrict__ bfv,
    const float* __restrict__ bz, const float* __restrict__ bo,
    const float* __restrict__ c0, const float* __restrict__ n0i,
    const float* __restrict__ m0,
    float* __restrict__ oc, float* __restrict__ on,
    float* __restrict__ oh, float* __restrict__ om)
{
  __shared__ __align__(16) u16 lds[8192];
  const int wid = xcd_swz(blockIdx.x, 4096);
  const int nt = wid & 31;          // 32-actual-col strip (x4 gates)
  const int mt = wid >> 5;          // 128-row tile
  f32x4 acc[4][4] = {};
  // x @ W^T (K=1024)
  gemm128(xb + (size_t)mt * 131072, 1024, Wint + nt * 131072, 1024, 1024,
          lds, acc);
  // + blockdiag(h0 @ R^T) (K=128; strip lies entirely in head nt>>2)
  gemm128(h0b + (size_t)mt * 131072 + (nt >> 2) * 128, 1024,
          Rint + nt * 16384, 128, 128, lds, acc);

  const int t = threadIdx.x, l = t & 63, w = t >> 6, wm = w >> 1, wc = w & 1;
  const int cc = nt * 32 + wc * 16 + (l & 15);
  const float biv = bi[cc], bfvv = bfv[cc], bzv = bz[cc], bov = bo[cc];
#pragma unroll
  for (int fm = 0; fm < 4; ++fm) {
    const int rbase = mt * 128 + wm * 64 + fm * 16 + (l >> 4) * 4;
#pragma unroll
    for (int r = 0; r < 4; ++r) {
      const size_t idx = (size_t)(rbase + r) * 1024 + cc;
      const float it = acc[fm][0][r] + biv;
      const float ft = acc[fm][1][r] + bfvv;
      const float zt = acc[fm][2][r] + bzv;
      const float ot = acc[fm][3][r] + bov;
      const float mp = m0[idx];
      const float mt_ = fmaxf(ft + mp, it);
      const float ie = __expf(it - mt_);
      const float fe = __expf(ft - mt_ + mp);
      const float ct = fe * c0[idx] + ie * tanhf(zt);
      const float ntv = fe * n0i[idx] + ie;
      const float ht = (ct / ntv) / (1.f + __expf(-ot));
      oc[idx] = ct; on[idx] = ntv; oh[idx] = ht; om[idx] = mt_;
    }
  }
}

// ---------------------------------------------------------------------------
// Kernel 4: GroupNorm over heads (128 ch / group), one wave per group -> bf16
// ---------------------------------------------------------------------------
__global__ __launch_bounds__(256) void gn_kernel(
    const float* __restrict__ h, const float* __restrict__ gw,
    const float* __restrict__ gb, u16* __restrict__ gnb)
{
  const int t = threadIdx.x, l = t & 63, w = t >> 6;
  for (int grp = blockIdx.x * 4 + w; grp < 16384 * 8; grp += gridDim.x * 4) {
    const int b = grp >> 3, hd = grp & 7;
    const float2 v = ((const float2*)(h + b * 1024 + hd * 128))[l];
    float s = v.x + v.y, q = v.x * v.x + v.y * v.y;
#pragma unroll
    for (int o = 32; o >= 1; o >>= 1) { s += __shfl_xor(s, o); q += __shfl_xor(q, o); }
    const float mu = s * (1.f / 128.f);
    const float var = q * (1.f / 128.f) - mu * mu;
    const float rstd = rsqrtf(var + 1e-5f);
    const float2 wv = ((const float2*)(gw + hd * 128))[l];
    const float2 bv = ((const float2*)(gb + hd * 128))[l];
    ushort2 o2;
    o2.x = f2bf((v.x - mu) * rstd * wv.x + bv.x);
    o2.y = f2bf((v.y - mu) * rstd * wv.y + bv.y);
    ((ushort2*)(gnb + b * 1024 + hd * 128))[l] = o2;
  }
}

// ---------------------------------------------------------------------------
// Kernel 5: up-proj; halves interleaved so (u1,u2) pair in-wave; GELU-GLU.
// Block: 128 rows x 64 actual x 2 halves.
// ---------------------------------------------------------------------------
__global__ __launch_bounds__(256, 3) void up_kernel(
    const u16* __restrict__ gnb, const u16* __restrict__ upint,
    const float* __restrict__ upb, u16* __restrict__ g)
{
  __shared__ __align__(16) u16 lds[8192];
  const int wid = xcd_swz(blockIdx.x, 2816);
  const int vt = wid % 22, mt = wid / 22;
  f32x4 acc[4][4] = {};
  gemm128(gnb + (size_t)mt * 131072, 1024, upint + vt * 131072, 1024, 1024,
          lds, acc);
  const int t = threadIdx.x, l = t & 63, w = t >> 6, wm = w >> 1, wc = w & 1;
#pragma unroll
  for (int fm = 0; fm < 4; ++fm) {
    const int rbase = mt * 128 + wm * 64 + fm * 16 + (l >> 4) * 4;
#pragma unroll
    for (int fn = 0; fn < 2; ++fn) {
      const int a = vt * 64 + wc * 32 + fn * 16 + (l & 15);
      const float b1 = (a < 1365) ? upb[a] : 0.f;
      const float b2 = (a < 1365) ? upb[1365 + a] : 0.f;
#pragma unroll
      for (int r = 0; r < 4; ++r) {
        const float u1 = acc[fm][fn][r] + b1;
        const float u2 = acc[fm][fn + 2][r] + b2;
        const float ge = 0.5f * u2 * (1.f + erff(u2 * 0.70710678118654752f));
        g[(size_t)(rbase + r) * 1408 + a] = f2bf(u1 + ge);
      }
    }
  }
}

// ---------------------------------------------------------------------------
// Kernel 6: down-proj (K=1408, zero-padded) + bias + residual -> d_out
// ---------------------------------------------------------------------------
__global__ __launch_bounds__(256, 3) void down_kernel(
    const u16* __restrict__ g, const u16* __restrict__ dnp,
    const float* __restrict__ dnb, const float* __restrict__ seq,
    float* __restrict__ out)
{
  __shared__ __align__(16) u16 lds[8192];
  const int wid = xcd_swz(blockIdx.x, 1024);
  const int nt = wid & 7, mt = wid >> 3;
  f32x4 acc[4][4] = {};
  gemm128(g + (size_t)mt * 180224, 1408, dnp + nt * 180224, 1408, 1408,
          lds, acc);
  const int t = threadIdx.x, l = t & 63, w = t >> 6, wm = w >> 1, wc = w & 1;
#pragma unroll
  for (int fm = 0; fm < 4; ++fm) {
    const int rbase = mt * 128 + wm * 64 + fm * 16 + (l >> 4) * 4;
#pragma unroll
    for (int fn = 0; fn < 4; ++fn) {
      const int cc = nt * 128 + wc * 64 + fn * 16 + (l & 15);
      const float bb = dnb[cc];
#pragma unroll
      for (int r = 0; r < 4; ++r) {
        const size_t idx = (size_t)(rbase + r) * 1024 + cc;
        out[idx] = acc[fm][fn][r] + bb + seq[idx];
      }
    }
  }
}

// ---------------------------------------------------------------------------
extern "C" void kernel_launch(void* const* d_in, const int* in_sizes, int n_in,
                              void* d_out, int out_size, void* d_ws, size_t ws_size,
                              hipStream_t stream) {
  const float* seq = (const float*)d_in[0];
  const float* c0  = (const float*)d_in[1];
  const float* n0i = (const float*)d_in[2];
  const float* h0  = (const float*)d_in[3];
  const float* m0  = (const float*)d_in[4];
  const float* lnw = (const float*)d_in[5];
  const float* lnb = (const float*)d_in[6];
  const float* Wz  = (const float*)d_in[7];
  const float* bz  = (const float*)d_in[8];
  const float* Wi  = (const float*)d_in[9];
  const float* bi  = (const float*)d_in[10];
  const float* Wo  = (const float*)d_in[11];
  const float* bo  = (const float*)d_in[12];
  const float* Wf  = (const float*)d_in[13];
  const float* bf_ = (const float*)d_in[14];
  const float* Rz  = (const float*)d_in[15];
  const float* Ri  = (const float*)d_in[16];
  const float* Ro  = (const float*)d_in[17];
  const float* Rf  = (const float*)d_in[18];
  const float* gw  = (const float*)d_in[19];
  const float* gb  = (const float*)d_in[20];
  const float* upw = (const float*)d_in[21];
  const float* upb = (const float*)d_in[22];
  const float* dnw = (const float*)d_in[23];
  const float* dnb = (const float*)d_in[24];

  char* ws = (char*)d_ws;
  u16* xb   = (u16*)(ws);              // 33,554,432 B (reused for gn output)
  u16* h0b  = (u16*)(ws + 33554432);   // 33,554,432 B
  u16* Wint = (u16*)(ws + 67108864);   //  8,388,608 B
  u16* Rint = (u16*)(ws + 75497472);   //  1,048,576 B
  u16* upc  = (u16*)(ws + 76546048);   //  5,767,168 B
  u16* dnp  = (u16*)(ws + 82313216);   //  2,883,584 B
  u16* g    = (u16*)(ws + 85196800);   // 46,137,344 B

  float* out = (float*)d_out;
  float* oc = out + 16777216;
  float* on = out + 2 * 16777216;
  float* oh = out + 3 * 16777216;
  float* om = out + 4 * 16777216;

  prep_kernel<<<dim3(2048), dim3(256), 0, stream>>>(
      Wi, Wf, Wz, Wo, Ri, Rf, Rz, Ro, upw, dnw, Wint, Rint, upc, dnp);
  ln_kernel<<<dim3(16384), dim3(256), 0, stream>>>(seq, h0, lnw, lnb, xb, h0b);
  gate_kernel<<<dim3(4096), dim3(256), 0, stream>>>(
      xb, h0b, Wint, Rint, bi, bf_, bz, bo, c0, n0i, m0, oc, on, oh, om);
  gn_kernel<<<dim3(2048), dim3(256), 0, stream>>>(oh, gw, gb, xb);
  up_kernel<<<dim3(2816), dim3(256), 0, stream>>>(xb, upc, upb, g);
  down_kernel<<<dim3(1024), dim3(256), 0, stream>>>(g, dnp, dnb, seq, out);
}

// Round 8
// 515.842 us; speedup vs baseline: 1.0932x; 1.0932x over previous
//
#include <hip/hip_runtime.h>
#include <hip/hip_bf16.h>
#include <cstdint>
#include <type_traits>

typedef __attribute__((ext_vector_type(8))) __bf16 bf16x8;
typedef __attribute__((ext_vector_type(8))) short short8;
typedef __attribute__((ext_vector_type(4))) float f32x4;
using u16 = unsigned short;

// ---- MFMA fragment-type autodetect ----
template <typename T, typename = void> struct mfma_ok : std::false_type {};
template <typename T>
struct mfma_ok<T, std::void_t<decltype(__builtin_amdgcn_mfma_f32_16x16x32_bf16(
    std::declval<T>(), std::declval<T>(), std::declval<f32x4>(), 0, 0, 0))>>
    : std::true_type {};
using frag_t = std::conditional_t<mfma_ok<bf16x8>::value, bf16x8, short8>;
static_assert(sizeof(frag_t) == 16, "frag must be 4 VGPRs");

template <typename T>
__device__ __forceinline__ f32x4 MFMA(T a, T b, f32x4 c) {
  return __builtin_amdgcn_mfma_f32_16x16x32_bf16(a, b, c, 0, 0, 0);
}

__device__ __forceinline__ void gl_lds16(const u16* g, u16* l) {
  __builtin_amdgcn_global_load_lds(
      (const __attribute__((address_space(1))) unsigned int*)g,
      (__attribute__((address_space(3))) unsigned int*)l, 16, 0, 0);
}

__device__ __forceinline__ u16 f2bf(float v) {
  __hip_bfloat16 h = __float2bfloat16(v);
  return __builtin_bit_cast(u16, h);
}

// bijective XCD swizzle (nwg % 8 == 0 for all our grids)
__device__ __forceinline__ int xcd_swz(int wid, int nwg) {
  return (wid & 7) * (nwg >> 3) + (wid >> 3);
}

// ---------------------------------------------------------------------------
// GEMM core v8 — k-slice ring-4 stream. 256x256(virtual) tile, 512 thr /
// 8 waves (2M x 4N), per-wave 128x64 -> acc[8][4]. K cut into 32-wide
// slices; LDS ring of 4 x 32KB slots (A 256x32 | B 256x32). Per phase s:
//   issue 4 gl_lds for slice s+2   (always 2 phases ahead)
//   12 ds_read_b128 of slice s     (swizzled, conflict-free)
//   32 MFMA (setprio-wrapped)
//   s_waitcnt vmcnt(4)             (slice s+1 landed; s+2 stays in flight)
//   s_barrier                      (ONE per phase)
// T4: vmcnt never drains to 0 until the stream tail. Loads are issued
// ~2 phases (~1100 cyc) before use -> HBM latency covered.
// Swizzle (rule 21, r2-verified 0-conflict): LDS[row][c] holds global
// chunk c ^ ((row>>1)&3); applied to gl_lds SOURCE (LDS dest linear) and
// to the ds_read chunk index (lane-constant since row%16 frag-aligned).
// A[row][k] row-major (lda); B[vcol][k] row-major (ldb). K % 32 == 0, K>=128.
// ---------------------------------------------------------------------------
__device__ __forceinline__ void gemm256(
    const u16* __restrict__ A, int lda,
    const u16* __restrict__ B, int ldb, int K,
    u16* lds, f32x4 (&acc)[8][4])
{
  const int t = threadIdx.x;
  const int l = t & 63;
  const int w = t >> 6;
  const int wm = w >> 2, wc = w & 3;

  // staging: thread t covers row (j*128 + t>>2), source chunk pre-swizzled
  const int cs = (t & 3) ^ ((t >> 3) & 3);          // (t&3) ^ ((row>>1)&3)
  const u16* gA = A + (t >> 2) * lda + cs * 8;
  const u16* gB = B + (t >> 2) * ldb + cs * 8;

  // fragment read offsets (swizzle reduces to lane constants)
  const int lr = l & 15, lk = l >> 4;
  const int ck = (lk ^ ((lr >> 1) & 3)) * 8;
  const int ab = (wm * 128 + lr) * 32 + ck;          // + fm*512
  const int bb = 8192 + (wc * 64 + lr) * 32 + ck;    // + fn*512

  const int ns = K >> 5;

#define STG(s) do {                                            \
    u16* s_ = lds + ((s) & 3) * 16384;                         \
    const u16* a_ = gA + (s) * 32;                             \
    const u16* b_ = gB + (s) * 32;                             \
    gl_lds16(a_,             s_ + w * 512);                    \
    gl_lds16(a_ + 128 * lda, s_ +  4096 + w * 512);            \
    gl_lds16(b_,             s_ +  8192 + w * 512);            \
    gl_lds16(b_ + 128 * ldb, s_ + 12288 + w * 512);            \
  } while (0)

  STG(0);
  STG(1);
  asm volatile("s_waitcnt vmcnt(4)" ::: "memory");   // slice 0 landed
  __builtin_amdgcn_s_barrier();

  for (int s = 0; s < ns; ++s) {
    u16* cur = lds + (s & 3) * 16384;
    if (s + 2 < ns) STG(s + 2);

    frag_t a[8], b[4];
#pragma unroll
    for (int fm = 0; fm < 8; ++fm)
      a[fm] = *(const frag_t*)(cur + ab + fm * 512);
#pragma unroll
    for (int fn = 0; fn < 4; ++fn)
      b[fn] = *(const frag_t*)(cur + bb + fn * 512);

    __builtin_amdgcn_s_setprio(1);
#pragma unroll
    for (int fn = 0; fn < 4; ++fn)
#pragma unroll
      for (int fm = 0; fm < 8; ++fm)
        acc[fm][fn] = MFMA(a[fm], b[fn], acc[fm][fn]);
    __builtin_amdgcn_s_setprio(0);

    if (s + 1 < ns) {
      if (s + 2 < ns) asm volatile("s_waitcnt vmcnt(4)" ::: "memory");
      else            asm volatile("s_waitcnt vmcnt(0)" ::: "memory");
      __builtin_amdgcn_s_barrier();
    }
  }
#undef STG
}

// ---------------------------------------------------------------------------
// Kernel 1: weight repack f32 -> bf16 with gate/half interleaving.
// Wint[16 strips][256 vcols][1024]   vcol = wc*64 + gate*16 + c16,
//                                    actual col = s*64 + wc*16 + c16
// Rint[16 strips][256 vcols][128]    same vcol map, col within head
// upint[11 tiles][256 vcols][1024]   vcol = wc*64 + half*32 + c32,
//                                    actual col = tile*128 + wc*32 + c32
// dnp[1024][1408] k-padded zeros
// ---------------------------------------------------------------------------
__global__ __launch_bounds__(256) void prep_kernel(
    const float* __restrict__ Wi, const float* __restrict__ Wf,
    const float* __restrict__ Wz, const float* __restrict__ Wo,
    const float* __restrict__ Ri, const float* __restrict__ Rf,
    const float* __restrict__ Rz, const float* __restrict__ Ro,
    const float* __restrict__ upw, const float* __restrict__ dnw,
    u16* __restrict__ Wint, u16* __restrict__ Rint,
    u16* __restrict__ upint, u16* __restrict__ dnp)
{
  const int stride = gridDim.x * 256;
  for (int i = blockIdx.x * 256 + threadIdx.x; i < 9043968; i += stride) {
    if (i < 4194304) {
      const int s = i >> 18, v = (i >> 10) & 255, k = i & 1023;
      const int wc = v >> 6, gsel = (v >> 4) & 3, c16 = v & 15;
      const int srcRow = s * 64 + wc * 16 + c16;
      const float* W = (gsel == 0) ? Wi : (gsel == 1) ? Wf : (gsel == 2) ? Wz : Wo;
      Wint[i] = f2bf(W[srcRow * 1024 + k]);
    } else if (i < 4718592) {
      const int j = i - 4194304;
      const int s = j >> 15, v = (j >> 7) & 255, k = j & 127;
      const int wc = v >> 6, gsel = (v >> 4) & 3, c16 = v & 15;
      const int head = s >> 1;
      const int colInHead = (s & 1) * 64 + wc * 16 + c16;
      const float* R = (gsel == 0) ? Ri : (gsel == 1) ? Rf : (gsel == 2) ? Rz : Ro;
      Rint[j] = f2bf(R[head * 16384 + colInHead * 128 + k]);
    } else if (i < 7602176) {
      const int j = i - 4718592;
      const int vcol = j >> 10, k = j & 1023;
      const int tile = vcol >> 8, wc = (vcol >> 6) & 3;
      const int half = (vcol >> 5) & 1, c32 = vcol & 31;
      const int a = tile * 128 + wc * 32 + c32;
      upint[j] = (a < 1365) ? f2bf(upw[(half * 1365 + a) * 1024 + k]) : (u16)0;
    } else {
      const int j = i - 7602176;
      const int row = j / 1408, k = j - row * 1408;
      dnp[j] = (k < 1365) ? f2bf(dnw[row * 1365 + k]) : (u16)0;
    }
  }
}

// ---------------------------------------------------------------------------
// Kernel 2: LayerNorm(seq) -> x bf16 ; h0 -> bf16. One row per block.
// ---------------------------------------------------------------------------
__global__ __launch_bounds__(256) void ln_kernel(
    const float* __restrict__ seq, const float* __restrict__ h0,
    const float* __restrict__ lnw, const float* __restrict__ lnb,
    u16* __restrict__ xb, u16* __restrict__ h0b)
{
  const int row = blockIdx.x;
  const int t = threadIdx.x;
  const float4 v = ((const float4*)(seq + (size_t)row * 1024))[t];
  float s = v.x + v.y + v.z + v.w;
  float q = v.x * v.x + v.y * v.y + v.z * v.z + v.w * v.w;
#pragma unroll
  for (int o = 32; o >= 1; o >>= 1) { s += __shfl_xor(s, o); q += __shfl_xor(q, o); }
  __shared__ float sm[8];
  const int l = t & 63, w = t >> 6;
  if (l == 0) { sm[w] = s; sm[4 + w] = q; }
  __syncthreads();
  s = sm[0] + sm[1] + sm[2] + sm[3];
  q = sm[4] + sm[5] + sm[6] + sm[7];
  const float mu = s * (1.f / 1024.f);
  const float var = q * (1.f / 1024.f) - mu * mu;
  const float rstd = rsqrtf(var + 1e-5f);
  const float4 wv = ((const float4*)lnw)[t];
  const float4 bv = ((const float4*)lnb)[t];
  ushort4 o4;
  o4.x = f2bf((v.x - mu) * rstd * wv.x + bv.x);
  o4.y = f2bf((v.y - mu) * rstd * wv.y + bv.y);
  o4.z = f2bf((v.z - mu) * rstd * wv.z + bv.z);
  o4.w = f2bf((v.w - mu) * rstd * wv.w + bv.w);
  ((ushort4*)(xb + (size_t)row * 1024))[t] = o4;
  const float4 h = ((const float4*)(h0 + (size_t)row * 1024))[t];
  ushort4 h4;
  h4.x = f2bf(h.x); h4.y = f2bf(h.y); h4.z = f2bf(h.z); h4.w = f2bf(h.w);
  ((ushort4*)(h0b + (size_t)row * 1024))[t] = h4;
}

// ---------------------------------------------------------------------------
// Kernel 3: fused 4-gate GEMM (+recurrent block-diag) + sLSTM pointwise.
// Block: 256 rows x strip(64 actual cols) x 4 gates (virtual N=256).
// Wave owns 128 rows x 16 actual cols x 4 gates -> pointwise in-register.
// ---------------------------------------------------------------------------
__global__ __launch_bounds__(512, 1) void gate_kernel(
    const u16* __restrict__ xb, const u16* __restrict__ h0b,
    const u16* __restrict__ Wint, const u16* __restrict__ Rint,
    const float* __restrict__ bi, const float* __restrict__ bfv,
    const float* __restrict__ bz, const float* __restrict__ bo,
    const float* __restrict__ c0, const float* __restrict__ n0i,
    const float* __restrict__ m0,
    float* __restrict__ oc, float* __restrict__ on,
    float* __restrict__ oh, float* __restrict__ om)
{
  __shared__ __align__(16) u16 lds[65536];
  const int wid = xcd_swz(blockIdx.x, 1024);
  const int s = wid & 15;           // 64-col strip
  const int m0r = (wid >> 4) * 256;
  f32x4 acc[8][4] = {};
  // x @ W^T (K=1024)
  gemm256(xb + (size_t)m0r * 1024, 1024, Wint + s * 262144, 1024, 1024, lds, acc);
  // + blockdiag(h0 @ R^T) (K=128; strip lies entirely in head s>>1)
  const int head = s >> 1;
  gemm256(h0b + (size_t)m0r * 1024 + head * 128, 1024,
          Rint + s * 32768, 128, 128, lds, acc);

  const int t = threadIdx.x, l = t & 63, w = t >> 6, wm = w >> 2, wc = w & 3;
  const int cc = s * 64 + wc * 16 + (l & 15);
  const float biv = bi[cc], bfvv = bfv[cc], bzv = bz[cc], bov = bo[cc];
#pragma unroll
  for (int fm = 0; fm < 8; ++fm) {
    const int rbase = m0r + wm * 128 + fm * 16 + (l >> 4) * 4;
#pragma unroll
    for (int r = 0; r < 4; ++r) {
      const size_t idx = (size_t)(rbase + r) * 1024 + cc;
      const float it = acc[fm][0][r] + biv;
      const float ft = acc[fm][1][r] + bfvv;
      const float zt = acc[fm][2][r] + bzv;
      const float ot = acc[fm][3][r] + bov;
      const float mp = m0[idx];
      const float mt = fmaxf(ft + mp, it);
      const float ie = __expf(it - mt);
      const float fe = __expf(ft - mt + mp);
      const float ct = fe * c0[idx] + ie * tanhf(zt);
      const float nt = fe * n0i[idx] + ie;
      const float ht = (ct / nt) / (1.f + __expf(-ot));
      oc[idx] = ct; on[idx] = nt; oh[idx] = ht; om[idx] = mt;
    }
  }
}

// ---------------------------------------------------------------------------
// Kernel 4: GroupNorm over heads (128 ch / group), one wave per group -> bf16
// ---------------------------------------------------------------------------
__global__ __launch_bounds__(256) void gn_kernel(
    const float* __restrict__ h, const float* __restrict__ gw,
    const float* __restrict__ gb, u16* __restrict__ gnb)
{
  const int t = threadIdx.x, l = t & 63, w = t >> 6;
  for (int grp = blockIdx.x * 4 + w; grp < 16384 * 8; grp += gridDim.x * 4) {
    const int b = grp >> 3, hd = grp & 7;
    const float2 v = ((const float2*)(h + b * 1024 + hd * 128))[l];
    float s = v.x + v.y, q = v.x * v.x + v.y * v.y;
#pragma unroll
    for (int o = 32; o >= 1; o >>= 1) { s += __shfl_xor(s, o); q += __shfl_xor(q, o); }
    const float mu = s * (1.f / 128.f);
    const float var = q * (1.f / 128.f) - mu * mu;
    const float rstd = rsqrtf(var + 1e-5f);
    const float2 wv = ((const float2*)(gw + hd * 128))[l];
    const float2 bv = ((const float2*)(gb + hd * 128))[l];
    ushort2 o2;
    o2.x = f2bf((v.x - mu) * rstd * wv.x + bv.x);
    o2.y = f2bf((v.y - mu) * rstd * wv.y + bv.y);
    ((ushort2*)(gnb + b * 1024 + hd * 128))[l] = o2;
  }
}

// ---------------------------------------------------------------------------
// Kernel 5: up-proj; halves interleaved so (u1,u2) pair in-wave; GELU-GLU.
// ---------------------------------------------------------------------------
__global__ __launch_bounds__(512, 1) void up_kernel(
    const u16* __restrict__ gnb, const u16* __restrict__ upint,
    const float* __restrict__ upb, u16* __restrict__ g)
{
  __shared__ __align__(16) u16 lds[65536];
  const int wid = xcd_swz(blockIdx.x, 704);
  const int vt = wid % 11, mt = wid / 11;
  const int m0r = mt * 256;
  f32x4 acc[8][4] = {};
  gemm256(gnb + (size_t)m0r * 1024, 1024, upint + vt * 262144, 1024, 1024,
          lds, acc);
  const int t = threadIdx.x, l = t & 63, w = t >> 6, wm = w >> 2, wc = w & 3;
#pragma unroll
  for (int fm = 0; fm < 8; ++fm) {
    const int rbase = m0r + wm * 128 + fm * 16 + (l >> 4) * 4;
#pragma unroll
    for (int fn = 0; fn < 2; ++fn) {
      const int a = vt * 128 + wc * 32 + fn * 16 + (l & 15);
      const float b1 = (a < 1365) ? upb[a] : 0.f;
      const float b2 = (a < 1365) ? upb[1365 + a] : 0.f;
#pragma unroll
      for (int r = 0; r < 4; ++r) {
        const float u1 = acc[fm][fn][r] + b1;
        const float u2 = acc[fm][fn + 2][r] + b2;
        const float ge = 0.5f * u2 * (1.f + erff(u2 * 0.70710678118654752f));
        g[(size_t)(rbase + r) * 1408 + a] = f2bf(u1 + ge);
      }
    }
  }
}

// ---------------------------------------------------------------------------
// Kernel 6: down-proj (K=1408, zero-padded) + bias + residual -> d_out
// ---------------------------------------------------------------------------
__global__ __launch_bounds__(512, 1) void down_kernel(
    const u16* __restrict__ g, const u16* __restrict__ dnp,
    const float* __restrict__ dnb, const float* __restrict__ seq,
    float* __restrict__ out)
{
  __shared__ __align__(16) u16 lds[65536];
  const int wid = xcd_swz(blockIdx.x, 256);
  const int nc = (wid & 3) * 256;
  const int m0r = (wid >> 2) * 256;
  f32x4 acc[8][4] = {};
  gemm256(g + (size_t)m0r * 1408, 1408, dnp + nc * 1408, 1408, 1408, lds, acc);
  const int t = threadIdx.x, l = t & 63, w = t >> 6, wm = w >> 2, wc = w & 3;
#pragma unroll
  for (int fm = 0; fm < 8; ++fm) {
    const int rbase = m0r + wm * 128 + fm * 16 + (l >> 4) * 4;
#pragma unroll
    for (int fn = 0; fn < 4; ++fn) {
      const int cc = nc + wc * 64 + fn * 16 + (l & 15);
      const float bb = dnb[cc];
#pragma unroll
      for (int r = 0; r < 4; ++r) {
        const size_t idx = (size_t)(rbase + r) * 1024 + cc;
        out[idx] = acc[fm][fn][r] + bb + seq[idx];
      }
    }
  }
}

// ---------------------------------------------------------------------------
extern "C" void kernel_launch(void* const* d_in, const int* in_sizes, int n_in,
                              void* d_out, int out_size, void* d_ws, size_t ws_size,
                              hipStream_t stream) {
  const float* seq = (const float*)d_in[0];
  const float* c0  = (const float*)d_in[1];
  const float* n0i = (const float*)d_in[2];
  const float* h0  = (const float*)d_in[3];
  const float* m0  = (const float*)d_in[4];
  const float* lnw = (const float*)d_in[5];
  const float* lnb = (const float*)d_in[6];
  const float* Wz  = (const float*)d_in[7];
  const float* bz  = (const float*)d_in[8];
  const float* Wi  = (const float*)d_in[9];
  const float* bi  = (const float*)d_in[10];
  const float* Wo  = (const float*)d_in[11];
  const float* bo  = (const float*)d_in[12];
  const float* Wf  = (const float*)d_in[13];
  const float* bf_ = (const float*)d_in[14];
  const float* Rz  = (const float*)d_in[15];
  const float* Ri  = (const float*)d_in[16];
  const float* Ro  = (const float*)d_in[17];
  const float* Rf  = (const float*)d_in[18];
  const float* gw  = (const float*)d_in[19];
  const float* gb  = (const float*)d_in[20];
  const float* upw = (const float*)d_in[21];
  const float* upb = (const float*)d_in[22];
  const float* dnw = (const float*)d_in[23];
  const float* dnb = (const float*)d_in[24];

  char* ws = (char*)d_ws;
  u16* xb   = (u16*)(ws);              // 33,554,432 B (reused for gn output)
  u16* h0b  = (u16*)(ws + 33554432);   // 33,554,432 B
  u16* Wint = (u16*)(ws + 67108864);   //  8,388,608 B
  u16* Rint = (u16*)(ws + 75497472);   //  1,048,576 B
  u16* upc  = (u16*)(ws + 76546048);   //  5,767,168 B
  u16* dnp  = (u16*)(ws + 82313216);   //  2,883,584 B
  u16* g    = (u16*)(ws + 85196800);   // 46,137,344 B

  float* out = (float*)d_out;
  float* oc = out + 16777216;
  float* on = out + 2 * 16777216;
  float* oh = out + 3 * 16777216;
  float* om = out + 4 * 16777216;

  prep_kernel<<<dim3(2048), dim3(256), 0, stream>>>(
      Wi, Wf, Wz, Wo, Ri, Rf, Rz, Ro, upw, dnw, Wint, Rint, upc, dnp);
  ln_kernel<<<dim3(16384), dim3(256), 0, stream>>>(seq, h0, lnw, lnb, xb, h0b);
  gate_kernel<<<dim3(1024), dim3(512), 0, stream>>>(
      xb, h0b, Wint, Rint, bi, bf_, bz, bo, c0, n0i, m0, oc, on, oh, om);
  gn_kernel<<<dim3(2048), dim3(256), 0, stream>>>(oh, gw, gb, xb);
  up_kernel<<<dim3(704), dim3(512), 0, stream>>>(xb, upc, upb, g);
  down_kernel<<<dim3(256), dim3(512), 0, stream>>>(g, dnp, dnb, seq, out);
}

// Round 9
// 515.540 us; speedup vs baseline: 1.0938x; 1.0006x over previous
//
#include <hip/hip_runtime.h>
#include <hip/hip_bf16.h>
#include <cstdint>
#include <type_traits>

typedef __attribute__((ext_vector_type(8))) __bf16 bf16x8;
typedef __attribute__((ext_vector_type(8))) short short8;
typedef __attribute__((ext_vector_type(4))) float f32x4;
using u16 = unsigned short;

// ---- MFMA fragment-type autodetect ----
template <typename T, typename = void> struct mfma_ok : std::false_type {};
template <typename T>
struct mfma_ok<T, std::void_t<decltype(__builtin_amdgcn_mfma_f32_16x16x32_bf16(
    std::declval<T>(), std::declval<T>(), std::declval<f32x4>(), 0, 0, 0))>>
    : std::true_type {};
using frag_t = std::conditional_t<mfma_ok<bf16x8>::value, bf16x8, short8>;
static_assert(sizeof(frag_t) == 16, "frag must be 4 VGPRs");

template <typename T>
__device__ __forceinline__ f32x4 MFMA(T a, T b, f32x4 c) {
  return __builtin_amdgcn_mfma_f32_16x16x32_bf16(a, b, c, 0, 0, 0);
}

__device__ __forceinline__ void gl_lds16(const u16* g, u16* l) {
  __builtin_amdgcn_global_load_lds(
      (const __attribute__((address_space(1))) unsigned int*)g,
      (__attribute__((address_space(3))) unsigned int*)l, 16, 0, 0);
}

__device__ __forceinline__ u16 f2bf(float v) {
  __hip_bfloat16 h = __float2bfloat16(v);
  return __builtin_bit_cast(u16, h);
}

// bijective XCD swizzle (nwg % 8 == 0 for all our grids)
__device__ __forceinline__ int xcd_swz(int wid, int nwg) {
  return (wid & 7) * (nwg >> 3) + (wid >> 3);
}

// ---------------------------------------------------------------------------
// GEMM core v9 — phase-ahead pipeline (T3+T4+T5). 256x256(virtual) tile,
// BK=64, 512 thr / 8 waves (2M x 4N), per-wave 128x64 -> acc[8][4].
// LDS: 2 x 64KB dbuf; buf layout [op A/B][k-half][256 rows][32 k] so each
// stage unit (16KB, 2 gl_lds/thread) is contiguous.
// 4 phases per K-tile. ds_reads are issued ONE PHASE AHEAD of the MFMAs
// that consume them (the m201 mechanism my r3-r8 attempts missed):
//   P0: read B.n23k0(cur) [for P1] ; stage A.k0(next) ; MFMA k0xn01
//       vmcnt(2 | 0 at tail) ; barrier       <- gates U2,U3(cur)
//   P1: read A.k1+B.n01k1(cur) [for P2] ; stage B.k0(next) ; MFMA k0xn23
//       barrier
//   P2: read B.n23k1(cur) [for P3] ; stage A.k1(next) ; MFMA k1xn01
//       vmcnt(2) ; barrier                   <- gates U0,U1(next)
//   P3: read A.k0+B.n01k0(NEXT buf) [for next P0] ; stage B.k1(next)
//       MFMA k1xn23 ; barrier
// vmcnt accounting (2 loads/unit, units staged P0..P3): at P0-end
// outstanding <= {U2,U3(cur... wait},U0(next)} = 6 -> vmcnt(2) leaves only
// U0(next) in flight, so U2,U3(cur) landed before P1 reads them. At P2-end
// outstanding <= {U0,U1,U2(next)} = 6 -> vmcnt(2) -> U0,U1(next) landed
// before P3 reads them. Queue never drains to 0 until the tail (T4).
// MFMA operands were read a phase earlier -> compiler emits counted lgkmcnt
// past the just-issued reads; MFMA issues immediately while new reads and
// stages complete underneath. Raw s_barrier (1/phase) + asm memory clobbers.
// Bank swizzle (rule 21, r8-verified 0-conflict): within each unit,
// LDS[row][c] holds global chunk c ^ ((row>>1)&3); applied to the gl_lds
// SOURCE (dest linear) and the ds_read chunk index (lane-constant).
// A[row][k] row-major (lda); B[vcol][k] row-major (ldb). K % 64 == 0.
// ---------------------------------------------------------------------------
#define VMC(n) asm volatile("s_waitcnt vmcnt(" #n ")" ::: "memory")
#define BARR() do { asm volatile("" ::: "memory");                        \
    __builtin_amdgcn_s_barrier();                                         \
    asm volatile("" ::: "memory"); } while (0)

__device__ __forceinline__ void gemm256(
    const u16* __restrict__ A, int lda,
    const u16* __restrict__ B, int ldb, int K,
    u16* lds, f32x4 (&acc)[8][4])
{
  const int t = threadIdx.x;
  const int l = t & 63;
  const int w = t >> 6;
  const int wm = w >> 2, wc = w & 3;

  // staging: thread t covers rows srow, srow+128; swizzled source chunk
  const int srow = t >> 2;
  const int cs = ((t & 3) ^ ((srow >> 1) & 3)) * 8;

  // fragment read lane constants (swizzle reduces to lane-only)
  const int lr = l & 15, lk = l >> 4;
  const int ck = (lk ^ ((lr >> 1) & 3)) * 8;

  u16* buf0 = lds;
  u16* buf1 = lds + 32768;
  const int nt = K >> 6;

#define STAGE_U(bufp, op, kh, kt) do {                                    \
    const u16* g0_ = (op) ? B : A;                                        \
    const int ld_ = (op) ? ldb : lda;                                     \
    const int kb_ = (kt) * 64 + (kh) * 32;                                \
    gl_lds16(g0_ + srow * ld_ + kb_ + cs,                                 \
             (bufp) + (op) * 16384 + (kh) * 8192 + w * 512);              \
    gl_lds16(g0_ + (srow + 128) * ld_ + kb_ + cs,                         \
             (bufp) + (op) * 16384 + (kh) * 8192 + 4096 + w * 512);       \
  } while (0)

#define RD_A(dst, bufp, kh) do {                                          \
    _Pragma("unroll")                                                     \
    for (int fm = 0; fm < 8; ++fm)                                        \
      dst[fm] = *(const frag_t*)((bufp) + (kh) * 8192 +                   \
                   (wm * 128 + fm * 16 + lr) * 32 + ck);                  \
  } while (0)

#define RD_B(dst, bufp, kh, nh) do {                                      \
    _Pragma("unroll")                                                     \
    for (int fn = 0; fn < 2; ++fn)                                        \
      dst[fn] = *(const frag_t*)((bufp) + 16384 + (kh) * 8192 +           \
                   (wc * 64 + (nh) * 32 + fn * 16 + lr) * 32 + ck);       \
  } while (0)

#define MMQ(AR, BR, n0) do {                                              \
    __builtin_amdgcn_s_setprio(1);                                        \
    _Pragma("unroll")                                                     \
    for (int fn = 0; fn < 2; ++fn)                                        \
      _Pragma("unroll")                                                   \
      for (int fm = 0; fm < 8; ++fm)                                      \
        acc[fm][(n0) + fn] = MFMA(AR[fm], BR[fn], acc[fm][(n0) + fn]);    \
    __builtin_amdgcn_s_setprio(0);                                        \
  } while (0)

  frag_t Ar0[8], Ar1[8], Br00[2], Br01[2], Br10[2], Br11[2];

  // ---- prologue: stage tile 0 into buf0; pre-read P0's operands ----
  STAGE_U(buf0, 0, 0, 0);   // U0 = A.k0
  STAGE_U(buf0, 1, 0, 0);   // U1 = B.k0
  STAGE_U(buf0, 0, 1, 0);   // U2 = A.k1
  STAGE_U(buf0, 1, 1, 0);   // U3 = B.k1
  VMC(4);                   // U0,U1 landed
  BARR();
  RD_A(Ar0, buf0, 0);
  RD_B(Br00, buf0, 0, 0);

  for (int kt = 0; kt < nt; ++kt) {
    u16* cur = (kt & 1) ? buf1 : buf0;
    u16* nxt = (kt & 1) ? buf0 : buf1;
    const bool more = (kt + 1 < nt);

    // ---- P0 ----
    RD_B(Br01, cur, 0, 1);
    if (more) STAGE_U(nxt, 0, 0, kt + 1);
    MMQ(Ar0, Br00, 0);
    if (more) { VMC(2); } else { VMC(0); }
    BARR();

    // ---- P1 ----
    RD_A(Ar1, cur, 1);
    RD_B(Br10, cur, 1, 0);
    if (more) STAGE_U(nxt, 1, 0, kt + 1);
    MMQ(Ar0, Br01, 2);
    BARR();

    // ---- P2 ----
    RD_B(Br11, cur, 1, 1);
    if (more) STAGE_U(nxt, 0, 1, kt + 1);
    MMQ(Ar1, Br10, 0);
    if (more) { VMC(2); }
    BARR();

    // ---- P3 ----
    if (more) {
      RD_A(Ar0, nxt, 0);
      RD_B(Br00, nxt, 0, 0);
      STAGE_U(nxt, 1, 1, kt + 1);
    }
    MMQ(Ar1, Br11, 2);
    BARR();
  }
#undef STAGE_U
#undef RD_A
#undef RD_B
#undef MMQ
}

// ---------------------------------------------------------------------------
// Kernel 1: weight repack f32 -> bf16 with gate/half interleaving.
// Wint[16 strips][256 vcols][1024]   vcol = wc*64 + gate*16 + c16,
//                                    actual col = s*64 + wc*16 + c16
// Rint[16 strips][256 vcols][128]    same vcol map, col within head
// upint[11 tiles][256 vcols][1024]   vcol = wc*64 + half*32 + c32,
//                                    actual col = tile*128 + wc*32 + c32
// dnp[1024][1408] k-padded zeros
// ---------------------------------------------------------------------------
__global__ __launch_bounds__(256) void prep_kernel(
    const float* __restrict__ Wi, const float* __restrict__ Wf,
    const float* __restrict__ Wz, const float* __restrict__ Wo,
    const float* __restrict__ Ri, const float* __restrict__ Rf,
    const float* __restrict__ Rz, const float* __restrict__ Ro,
    const float* __restrict__ upw, const float* __restrict__ dnw,
    u16* __restrict__ Wint, u16* __restrict__ Rint,
    u16* __restrict__ upint, u16* __restrict__ dnp)
{
  const int stride = gridDim.x * 256;
  for (int i = blockIdx.x * 256 + threadIdx.x; i < 9043968; i += stride) {
    if (i < 4194304) {
      const int s = i >> 18, v = (i >> 10) & 255, k = i & 1023;
      const int wc = v >> 6, gsel = (v >> 4) & 3, c16 = v & 15;
      const int srcRow = s * 64 + wc * 16 + c16;
      const float* W = (gsel == 0) ? Wi : (gsel == 1) ? Wf : (gsel == 2) ? Wz : Wo;
      Wint[i] = f2bf(W[srcRow * 1024 + k]);
    } else if (i < 4718592) {
      const int j = i - 4194304;
      const int s = j >> 15, v = (j >> 7) & 255, k = j & 127;
      const int wc = v >> 6, gsel = (v >> 4) & 3, c16 = v & 15;
      const int head = s >> 1;
      const int colInHead = (s & 1) * 64 + wc * 16 + c16;
      const float* R = (gsel == 0) ? Ri : (gsel == 1) ? Rf : (gsel == 2) ? Rz : Ro;
      Rint[j] = f2bf(R[head * 16384 + colInHead * 128 + k]);
    } else if (i < 7602176) {
      const int j = i - 4718592;
      const int vcol = j >> 10, k = j & 1023;
      const int tile = vcol >> 8, wc = (vcol >> 6) & 3;
      const int half = (vcol >> 5) & 1, c32 = vcol & 31;
      const int a = tile * 128 + wc * 32 + c32;
      upint[j] = (a < 1365) ? f2bf(upw[(half * 1365 + a) * 1024 + k]) : (u16)0;
    } else {
      const int j = i - 7602176;
      const int row = j / 1408, k = j - row * 1408;
      dnp[j] = (k < 1365) ? f2bf(dnw[row * 1365 + k]) : (u16)0;
    }
  }
}

// ---------------------------------------------------------------------------
// Kernel 2: LayerNorm(seq) -> x bf16 ; h0 -> bf16. One row per block.
// ---------------------------------------------------------------------------
__global__ __launch_bounds__(256) void ln_kernel(
    const float* __restrict__ seq, const float* __restrict__ h0,
    const float* __restrict__ lnw, const float* __restrict__ lnb,
    u16* __restrict__ xb, u16* __restrict__ h0b)
{
  const int row = blockIdx.x;
  const int t = threadIdx.x;
  const float4 v = ((const float4*)(seq + (size_t)row * 1024))[t];
  float s = v.x + v.y + v.z + v.w;
  float q = v.x * v.x + v.y * v.y + v.z * v.z + v.w * v.w;
#pragma unroll
  for (int o = 32; o >= 1; o >>= 1) { s += __shfl_xor(s, o); q += __shfl_xor(q, o); }
  __shared__ float sm[8];
  const int l = t & 63, w = t >> 6;
  if (l == 0) { sm[w] = s; sm[4 + w] = q; }
  __syncthreads();
  s = sm[0] + sm[1] + sm[2] + sm[3];
  q = sm[4] + sm[5] + sm[6] + sm[7];
  const float mu = s * (1.f / 1024.f);
  const float var = q * (1.f / 1024.f) - mu * mu;
  const float rstd = rsqrtf(var + 1e-5f);
  const float4 wv = ((const float4*)lnw)[t];
  const float4 bv = ((const float4*)lnb)[t];
  ushort4 o4;
  o4.x = f2bf((v.x - mu) * rstd * wv.x + bv.x);
  o4.y = f2bf((v.y - mu) * rstd * wv.y + bv.y);
  o4.z = f2bf((v.z - mu) * rstd * wv.z + bv.z);
  o4.w = f2bf((v.w - mu) * rstd * wv.w + bv.w);
  ((ushort4*)(xb + (size_t)row * 1024))[t] = o4;
  const float4 h = ((const float4*)(h0 + (size_t)row * 1024))[t];
  ushort4 h4;
  h4.x = f2bf(h.x); h4.y = f2bf(h.y); h4.z = f2bf(h.z); h4.w = f2bf(h.w);
  ((ushort4*)(h0b + (size_t)row * 1024))[t] = h4;
}

// ---------------------------------------------------------------------------
// Kernel 3: fused 4-gate GEMM (+recurrent block-diag) + sLSTM pointwise.
// Block: 256 rows x strip(64 actual cols) x 4 gates (virtual N=256).
// Wave owns 128 rows x 16 actual cols x 4 gates -> pointwise in-register.
// ---------------------------------------------------------------------------
__global__ __launch_bounds__(512, 1) void gate_kernel(
    const u16* __restrict__ xb, const u16* __restrict__ h0b,
    const u16* __restrict__ Wint, const u16* __restrict__ Rint,
    const float* __restrict__ bi, const float* __restrict__ bfv,
    const float* __restrict__ bz, const float* __restrict__ bo,
    const float* __restrict__ c0, const float* __restrict__ n0i,
    const float* __restrict__ m0,
    float* __restrict__ oc, float* __restrict__ on,
    float* __restrict__ oh, float* __restrict__ om)
{
  __shared__ __align__(16) u16 lds[65536];
  const int wid = xcd_swz(blockIdx.x, 1024);
  const int s = wid & 15;           // 64-col strip
  const int m0r = (wid >> 4) * 256;
  f32x4 acc[8][4] = {};
  // x @ W^T (K=1024)
  gemm256(xb + (size_t)m0r * 1024, 1024, Wint + s * 262144, 1024, 1024, lds, acc);
  // + blockdiag(h0 @ R^T) (K=128; strip lies entirely in head s>>1)
  const int head = s >> 1;
  gemm256(h0b + (size_t)m0r * 1024 + head * 128, 1024,
          Rint + s * 32768, 128, 128, lds, acc);

  const int t = threadIdx.x, l = t & 63, w = t >> 6, wm = w >> 2, wc = w & 3;
  const int cc = s * 64 + wc * 16 + (l & 15);
  const float biv = bi[cc], bfvv = bfv[cc], bzv = bz[cc], bov = bo[cc];
#pragma unroll
  for (int fm = 0; fm < 8; ++fm) {
    const int rbase = m0r + wm * 128 + fm * 16 + (l >> 4) * 4;
#pragma unroll
    for (int r = 0; r < 4; ++r) {
      const size_t idx = (size_t)(rbase + r) * 1024 + cc;
      const float it = acc[fm][0][r] + biv;
      const float ft = acc[fm][1][r] + bfvv;
      const float zt = acc[fm][2][r] + bzv;
      const float ot = acc[fm][3][r] + bov;
      const float mp = m0[idx];
      const float mt = fmaxf(ft + mp, it);
      const float ie = __expf(it - mt);
      const float fe = __expf(ft - mt + mp);
      const float ct = fe * c0[idx] + ie * tanhf(zt);
      const float nt = fe * n0i[idx] + ie;
      const float ht = (ct / nt) / (1.f + __expf(-ot));
      oc[idx] = ct; on[idx] = nt; oh[idx] = ht; om[idx] = mt;
    }
  }
}

// ---------------------------------------------------------------------------
// Kernel 4: GroupNorm over heads (128 ch / group), one wave per group -> bf16
// ---------------------------------------------------------------------------
__global__ __launch_bounds__(256) void gn_kernel(
    const float* __restrict__ h, const float* __restrict__ gw,
    const float* __restrict__ gb, u16* __restrict__ gnb)
{
  const int t = threadIdx.x, l = t & 63, w = t >> 6;
  for (int grp = blockIdx.x * 4 + w; grp < 16384 * 8; grp += gridDim.x * 4) {
    const int b = grp >> 3, hd = grp & 7;
    const float2 v = ((const float2*)(h + b * 1024 + hd * 128))[l];
    float s = v.x + v.y, q = v.x * v.x + v.y * v.y;
#pragma unroll
    for (int o = 32; o >= 1; o >>= 1) { s += __shfl_xor(s, o); q += __shfl_xor(q, o); }
    const float mu = s * (1.f / 128.f);
    const float var = q * (1.f / 128.f) - mu * mu;
    const float rstd = rsqrtf(var + 1e-5f);
    const float2 wv = ((const float2*)(gw + hd * 128))[l];
    const float2 bv = ((const float2*)(gb + hd * 128))[l];
    ushort2 o2;
    o2.x = f2bf((v.x - mu) * rstd * wv.x + bv.x);
    o2.y = f2bf((v.y - mu) * rstd * wv.y + bv.y);
    ((ushort2*)(gnb + b * 1024 + hd * 128))[l] = o2;
  }
}

// ---------------------------------------------------------------------------
// Kernel 5: up-proj; halves interleaved so (u1,u2) pair in-wave; GELU-GLU.
// ---------------------------------------------------------------------------
__global__ __launch_bounds__(512, 1) void up_kernel(
    const u16* __restrict__ gnb, const u16* __restrict__ upint,
    const float* __restrict__ upb, u16* __restrict__ g)
{
  __shared__ __align__(16) u16 lds[65536];
  const int wid = xcd_swz(blockIdx.x, 704);
  const int vt = wid % 11, mt = wid / 11;
  const int m0r = mt * 256;
  f32x4 acc[8][4] = {};
  gemm256(gnb + (size_t)m0r * 1024, 1024, upint + vt * 262144, 1024, 1024,
          lds, acc);
  const int t = threadIdx.x, l = t & 63, w = t >> 6, wm = w >> 2, wc = w & 3;
#pragma unroll
  for (int fm = 0; fm < 8; ++fm) {
    const int rbase = m0r + wm * 128 + fm * 16 + (l >> 4) * 4;
#pragma unroll
    for (int fn = 0; fn < 2; ++fn) {
      const int a = vt * 128 + wc * 32 + fn * 16 + (l & 15);
      const float b1 = (a < 1365) ? upb[a] : 0.f;
      const float b2 = (a < 1365) ? upb[1365 + a] : 0.f;
#pragma unroll
      for (int r = 0; r < 4; ++r) {
        const float u1 = acc[fm][fn][r] + b1;
        const float u2 = acc[fm][fn + 2][r] + b2;
        const float ge = 0.5f * u2 * (1.f + erff(u2 * 0.70710678118654752f));
        g[(size_t)(rbase + r) * 1408 + a] = f2bf(u1 + ge);
      }
    }
  }
}

// ---------------------------------------------------------------------------
// Kernel 6: down-proj (K=1408, zero-padded) + bias + residual -> d_out
// ---------------------------------------------------------------------------
__global__ __launch_bounds__(512, 1) void down_kernel(
    const u16* __restrict__ g, const u16* __restrict__ dnp,
    const float* __restrict__ dnb, const float* __restrict__ seq,
    float* __restrict__ out)
{
  __shared__ __align__(16) u16 lds[65536];
  const int wid = xcd_swz(blockIdx.x, 256);
  const int nc = (wid & 3) * 256;
  const int m0r = (wid >> 2) * 256;
  f32x4 acc[8][4] = {};
  gemm256(g + (size_t)m0r * 1408, 1408, dnp + nc * 1408, 1408, 1408, lds, acc);
  const int t = threadIdx.x, l = t & 63, w = t >> 6, wm = w >> 2, wc = w & 3;
#pragma unroll
  for (int fm = 0; fm < 8; ++fm) {
    const int rbase = m0r + wm * 128 + fm * 16 + (l >> 4) * 4;
#pragma unroll
    for (int fn = 0; fn < 4; ++fn) {
      const int cc = nc + wc * 64 + fn * 16 + (l & 15);
      const float bb = dnb[cc];
#pragma unroll
      for (int r = 0; r < 4; ++r) {
        const size_t idx = (size_t)(rbase + r) * 1024 + cc;
        out[idx] = acc[fm][fn][r] + bb + seq[idx];
      }
    }
  }
}

// ---------------------------------------------------------------------------
extern "C" void kernel_launch(void* const* d_in, const int* in_sizes, int n_in,
                              void* d_out, int out_size, void* d_ws, size_t ws_size,
                              hipStream_t stream) {
  const float* seq = (const float*)d_in[0];
  const float* c0  = (const float*)d_in[1];
  const float* n0i = (const float*)d_in[2];
  const float* h0  = (const float*)d_in[3];
  const float* m0  = (const float*)d_in[4];
  const float* lnw = (const float*)d_in[5];
  const float* lnb = (const float*)d_in[6];
  const float* Wz  = (const float*)d_in[7];
  const float* bz  = (const float*)d_in[8];
  const float* Wi  = (const float*)d_in[9];
  const float* bi  = (const float*)d_in[10];
  const float* Wo  = (const float*)d_in[11];
  const float* bo  = (const float*)d_in[12];
  const float* Wf  = (const float*)d_in[13];
  const float* bf_ = (const float*)d_in[14];
  const float* Rz  = (const float*)d_in[15];
  const float* Ri  = (const float*)d_in[16];
  const float* Ro  = (const float*)d_in[17];
  const float* Rf  = (const float*)d_in[18];
  const float* gw  = (const float*)d_in[19];
  const float* gb  = (const float*)d_in[20];
  const float* upw = (const float*)d_in[21];
  const float* upb = (const float*)d_in[22];
  const float* dnw = (const float*)d_in[23];
  const float* dnb = (const float*)d_in[24];

  char* ws = (char*)d_ws;
  u16* xb   = (u16*)(ws);              // 33,554,432 B (reused for gn output)
  u16* h0b  = (u16*)(ws + 33554432);   // 33,554,432 B
  u16* Wint = (u16*)(ws + 67108864);   //  8,388,608 B
  u16* Rint = (u16*)(ws + 75497472);   //  1,048,576 B
  u16* upc  = (u16*)(ws + 76546048);   //  5,767,168 B
  u16* dnp  = (u16*)(ws + 82313216);   //  2,883,584 B
  u16* g    = (u16*)(ws + 85196800);   // 46,137,344 B

  float* out = (float*)d_out;
  float* oc = out + 16777216;
  float* on = out + 2 * 16777216;
  float* oh = out + 3 * 16777216;
  float* om = out + 4 * 16777216;

  prep_kernel<<<dim3(2048), dim3(256), 0, stream>>>(
      Wi, Wf, Wz, Wo, Ri, Rf, Rz, Ro, upw, dnw, Wint, Rint, upc, dnp);
  ln_kernel<<<dim3(16384), dim3(256), 0, stream>>>(seq, h0, lnw, lnb, xb, h0b);
  gate_kernel<<<dim3(1024), dim3(512), 0, stream>>>(
      xb, h0b, Wint, Rint, bi, bf_, bz, bo, c0, n0i, m0, oc, on, oh, om);
  gn_kernel<<<dim3(2048), dim3(256), 0, stream>>>(oh, gw, gb, xb);
  up_kernel<<<dim3(704), dim3(512), 0, stream>>>(xb, upc, upb, g);
  down_kernel<<<dim3(256), dim3(512), 0, stream>>>(g, dnp, dnb, seq, out);
}